// Round 13
// baseline (802.871 us; speedup 1.0000x reference)
//
#include <hip/hip_runtime.h>
#include <cstdint>

typedef __attribute__((ext_vector_type(8))) __bf16 bf16x8;
typedef __attribute__((ext_vector_type(4))) float f32x4;
typedef __attribute__((ext_vector_type(8))) unsigned short u16x8;

#define SEQ 4096
// Q/K row stride in shorts. 1088 = 2176B = 17*128B: NOT a power of two --
// r7 lesson: 1024 (2048B) collapses K-staging rows onto few L2/HBM channels
// (attn 121.5 -> 134.2 us). Odd multiple of 128B rotates rows across channels.
#define QKV_LD 1088
// Vt row stride: SEQ=4096 exactly. r11 lesson: padding to 4160 pushed the
// per-batch Vt slice past the 4 MB per-XCD L2 and cost +16 us. V is protected
// by exact L2 residency.

__device__ __forceinline__ unsigned short f2bf(float f) {
  unsigned u = __builtin_bit_cast(unsigned, f);
  u += 0x7fffu + ((u >> 16) & 1u);
  return (unsigned short)(u >> 16);
}

__device__ __forceinline__ float bf2f(unsigned short h) {
  return __builtin_bit_cast(float, (unsigned)h << 16);
}

// async global->LDS, 16B per lane. LDS dest = wave-uniform base + lane*16.
__device__ __forceinline__ void async_copy16(const void* g, const void* lds) {
  __builtin_amdgcn_global_load_lds(
      (const __attribute__((address_space(1))) void*)(uintptr_t)g,
      (__attribute__((address_space(3))) void*)(unsigned)(uintptr_t)lds,
      16, 0, 0);
}

// cross-lane pair swaps (gfx950). After pl32: a lanes[32:63] <-> b lanes[0:31].
// After pl16: a lanes[16:31] <-> b lanes[0:15] and a[48:63] <-> b[32:47].
__device__ __forceinline__ void pl32swap(unsigned& a, unsigned& b) {
#if __has_builtin(__builtin_amdgcn_permlane32_swap)
  typedef __attribute__((ext_vector_type(2))) unsigned u32x2;
  u32x2 r = __builtin_amdgcn_permlane32_swap(a, b, false, false);
  a = r[0]; b = r[1];
#else
  asm("v_permlane32_swap_b32 %0, %1" : "+v"(a), "+v"(b));
#endif
}
__device__ __forceinline__ void pl16swap(unsigned& a, unsigned& b) {
#if __has_builtin(__builtin_amdgcn_permlane16_swap)
  typedef __attribute__((ext_vector_type(2))) unsigned u32x2;
  u32x2 r = __builtin_amdgcn_permlane16_swap(a, b, false, false);
  a = r[0]; b = r[1];
#else
  asm("v_permlane16_swap_b32 %0, %1" : "+v"(a), "+v"(b));
#endif
}

// single launch: x (8192 blocks) + all four 512x512 weights (1024 blocks)
__global__ void cvt_all(const float* __restrict__ x,
                        const float* __restrict__ Wq, const float* __restrict__ Wk,
                        const float* __restrict__ Wv, const float* __restrict__ Wo,
                        unsigned short* __restrict__ xb, unsigned short* __restrict__ wqk,
                        unsigned short* __restrict__ wv, unsigned short* __restrict__ wo)
{
  int bid = blockIdx.x;
  const float* src; unsigned short* dst; int i;
  if (bid < 8192) {
    src = x; dst = xb; i = (bid * 256 + threadIdx.x) * 4;
  } else {
    int b2 = bid - 8192;          // 0..1023, 256 blocks per weight
    int y = b2 >> 8;
    src = (y == 0) ? Wq : (y == 1) ? Wk : (y == 2) ? Wv : Wo;
    dst = (y == 0) ? wqk : (y == 1) ? wqk + 262144 : (y == 2) ? wv : wo;
    i = ((b2 & 255) * 256 + threadIdx.x) * 4;
  }
  float4 v = *(const float4*)(src + i);
  ushort4 o;
  o.x = f2bf(v.x); o.y = f2bf(v.y); o.z = f2bf(v.z); o.w = f2bf(v.w);
  *(ushort4*)(dst + i) = o;
}

// C[m,n] = sum_k A[m,k] * B[n,k]  (A: lda=512, B: ldb=512, both bf16, K=512)
// Double-buffered k-loop (r9). Used only for the fallback proj path.
template <bool F32OUT>
__global__ __launch_bounds__(256, 2) void gemm_bt(
    const unsigned short* __restrict__ A, const unsigned short* __restrict__ B,
    void* __restrict__ C, int ldc)
{
  __shared__ unsigned short As[2][4096];
  __shared__ unsigned short Bs[2][4096];
  const int tid = threadIdx.x;
  const int lane = tid & 63;
  const int w = tid >> 6;
  const int l15 = lane & 15, quad = lane >> 4;
  const int wm = w & 1, wn = w >> 1;
  const long m0 = (long)blockIdx.x * 128;
  const long n0 = (long)blockIdx.y * 128;

  f32x4 acc[4][4] = {};

#define GB_STAGE(KT, BI)                                                            \
  {                                                                                 \
    int c = tid;                                                                    \
    int row = c >> 2, chl = c & 3;                                                  \
    int gch = (chl - (row >> 1)) & 3;                                               \
    async_copy16(A + (m0 + row) * 512 + (KT) * 32 + gch * 8, As[BI] + c * 8);       \
    async_copy16(B + (n0 + row) * 512 + (KT) * 32 + gch * 8, Bs[BI] + c * 8);       \
    c = tid + 256;                                                                  \
    row = c >> 2; chl = c & 3;                                                      \
    gch = (chl - (row >> 1)) & 3;                                                   \
    async_copy16(A + (m0 + row) * 512 + (KT) * 32 + gch * 8, As[BI] + c * 8);       \
    async_copy16(B + (n0 + row) * 512 + (KT) * 32 + gch * 8, Bs[BI] + c * 8);       \
  }

  GB_STAGE(0, 0);
  int bi = 0;
  for (int kt = 0; kt < 16; ++kt) {
    __syncthreads();
    if (kt + 1 < 16) GB_STAGE(kt + 1, bi ^ 1);

    bf16x8 af[4], bfr[4];
#pragma unroll
    for (int mt = 0; mt < 4; ++mt) {
      int row = wm * 64 + mt * 16 + l15;
      int chl = (quad + (row >> 1)) & 3;
      af[mt] = *(const bf16x8*)(As[bi] + row * 32 + chl * 8);
    }
#pragma unroll
    for (int nt = 0; nt < 4; ++nt) {
      int row = wn * 64 + nt * 16 + l15;
      int chl = (quad + (row >> 1)) & 3;
      bfr[nt] = *(const bf16x8*)(Bs[bi] + row * 32 + chl * 8);
    }
#pragma unroll
    for (int mt = 0; mt < 4; ++mt)
#pragma unroll
      for (int nt = 0; nt < 4; ++nt)
        acc[mt][nt] = __builtin_amdgcn_mfma_f32_16x16x32_bf16(af[mt], bfr[nt], acc[mt][nt], 0, 0, 0);
    bi ^= 1;
  }
#undef GB_STAGE

#pragma unroll
  for (int mt = 0; mt < 4; ++mt)
#pragma unroll
    for (int nt = 0; nt < 4; ++nt)
#pragma unroll
      for (int r = 0; r < 4; ++r) {
        long row = m0 + wm * 64 + mt * 16 + quad * 4 + r;
        long col = n0 + wn * 64 + nt * 16 + l15;
        float v = acc[mt][nt][r];
        if (F32OUT) ((float*)C)[row * ldc + col] = v;
        else        ((unsigned short*)C)[row * ldc + col] = f2bf(v);
      }
}

// Merged QK + V^T GEMM in one launch (r10): blocks 0..1023 compute
// qkv[s][0..1023] = [x@Wq^T | x@Wk^T]; blocks 1024..1535 compute
// Vt[b][d][s] = sum_k Wv[d,k]*x[b,s,k] (row stride SEQ). Same body,
// operands picked per block; V blocks backfill CUs during the QK tail.
__global__ __launch_bounds__(256, 2) void gemm_qkv(
    const unsigned short* __restrict__ xb, const unsigned short* __restrict__ wqk,
    unsigned short* __restrict__ qkv,
    const unsigned short* __restrict__ wv, unsigned short* __restrict__ vt)
{
  __shared__ unsigned short As[2][4096];
  __shared__ unsigned short Bs[2][4096];
  const unsigned short *A, *B;
  unsigned short* C;
  int ldc;
  long m0, n0;
  {
    int bid = blockIdx.x;
    if (bid < 1024) {
      A = xb; B = wqk; C = qkv; ldc = QKV_LD;
      m0 = (long)(bid & 127) * 128;
      n0 = (long)(bid >> 7) * 128;
    } else {
      int b2 = bid - 1024;               // 0..511
      int z = b2 >> 7;                   // batch
      A = wv; B = xb + (long)z * SEQ * 512; C = vt + (long)z * 512 * SEQ; ldc = SEQ;
      m0 = (long)(b2 & 3) * 128;
      n0 = (long)((b2 >> 2) & 31) * 128;
    }
  }
  const int tid = threadIdx.x;
  const int lane = tid & 63;
  const int w = tid >> 6;
  const int l15 = lane & 15, quad = lane >> 4;
  const int wm = w & 1, wn = w >> 1;

  f32x4 acc[4][4] = {};

#define GQ_STAGE(KT, BI)                                                            \
  {                                                                                 \
    int c = tid;                                                                    \
    int row = c >> 2, chl = c & 3;                                                  \
    int gch = (chl - (row >> 1)) & 3;                                               \
    async_copy16(A + (m0 + row) * 512 + (KT) * 32 + gch * 8, As[BI] + c * 8);       \
    async_copy16(B + (n0 + row) * 512 + (KT) * 32 + gch * 8, Bs[BI] + c * 8);       \
    c = tid + 256;                                                                  \
    row = c >> 2; chl = c & 3;                                                      \
    gch = (chl - (row >> 1)) & 3;                                                   \
    async_copy16(A + (m0 + row) * 512 + (KT) * 32 + gch * 8, As[BI] + c * 8);       \
    async_copy16(B + (n0 + row) * 512 + (KT) * 32 + gch * 8, Bs[BI] + c * 8);       \
  }

  GQ_STAGE(0, 0);
  int bi = 0;
  for (int kt = 0; kt < 16; ++kt) {
    __syncthreads();
    if (kt + 1 < 16) GQ_STAGE(kt + 1, bi ^ 1);

    bf16x8 af[4], bfr[4];
#pragma unroll
    for (int mt = 0; mt < 4; ++mt) {
      int row = wm * 64 + mt * 16 + l15;
      int chl = (quad + (row >> 1)) & 3;
      af[mt] = *(const bf16x8*)(As[bi] + row * 32 + chl * 8);
    }
#pragma unroll
    for (int nt = 0; nt < 4; ++nt) {
      int row = wn * 64 + nt * 16 + l15;
      int chl = (quad + (row >> 1)) & 3;
      bfr[nt] = *(const bf16x8*)(Bs[bi] + row * 32 + chl * 8);
    }
#pragma unroll
    for (int mt = 0; mt < 4; ++mt)
#pragma unroll
      for (int nt = 0; nt < 4; ++nt)
        acc[mt][nt] = __builtin_amdgcn_mfma_f32_16x16x32_bf16(af[mt], bfr[nt], acc[mt][nt], 0, 0, 0);
    bi ^= 1;
  }
#undef GQ_STAGE

#pragma unroll
  for (int mt = 0; mt < 4; ++mt)
#pragma unroll
    for (int nt = 0; nt < 4; ++nt)
#pragma unroll
      for (int r = 0; r < 4; ++r) {
        long row = m0 + wm * 64 + mt * 16 + quad * 4 + r;
        long col = n0 + wn * 64 + nt * 16 + l15;
        C[row * ldc + col] = f2bf(acc[mt][nt][r]);
      }
}

// Flash attention, causal. r13: SAME math/layout/swizzles/epilogue as the
// verified r12 kernel (Q-tile 128, 512 threads, 8 waves x 16 q-rows,
// split-K x4, XCD-aware, STATIC-MAX softmax, swapped QK^T, in-register P
// transpose), but SINGLE-buffered K+V (64 KB LDS) -> 2 co-resident blocks/CU
// (16 waves, 4/SIMD). Rationale: at 1 block/CU the step time (~8.3K cy) is
// ~75% stall (identified work ~1.7K cy) -- all 8 waves share one barrier
// domain and phase. A second INDEPENDENT block fills the stalls. Unlike r6's
// failed attempt, the Q-tile is unchanged (traffic constant) and the split
// ordering pairs large with small: block f (qt=31-j) co-dispatches with
// f+256 (qt=j), so each CU's pair sums to ~32 steps (balanced makespan).
// launch_bounds(512,4) caps VGPR at 128 (the kernel already fits 128).
__global__ __launch_bounds__(512, 4) void attn(const unsigned short* __restrict__ QKV,
                                               const unsigned short* __restrict__ Vt,
                                               unsigned short* __restrict__ part0,
                                               unsigned short* __restrict__ part1,
                                               unsigned short* __restrict__ part2,
                                               unsigned short* __restrict__ part3,
                                               float* __restrict__ mlbuf)
{
  extern __shared__ unsigned short smem[];
  // layout (shorts): K @0 (32KB), V @16384 (32KB) -- single buffer
  const int tid = threadIdx.x;
  const int lane = tid & 63, w = tid >> 6;
  const int l15 = lane & 15, quad = lane >> 4;

  const int f = blockIdx.x;
  const int xcd = f & 7;
  const int j = f >> 3;            // 0..63 within XCD slice
  const int bat = xcd >> 1;        // batch -> XCD pair
  const int half = xcd & 1;
  int qt, sv;
  // sv0 largest-first, sv1 smallest-first: co-dispatched pair (j, j+32) has
  // qt = 31-j and j -> constant-sum work for the 2-resident schedule.
  if (j < 32) { qt = 31 - j; sv = 0; }
  else        { qt = j - 32; sv = 1; }
  const int split = half * 2 + sv;

  const int q0 = qt * 128;
  const int wrow0 = q0 + w * 16;
  // e = exp2(raw * SCALE * log2e - 12 * log2e)
  const float C1 = 0.04419417382415922f * 1.4426950408889634f;
  const float C2 = -12.0f * 1.4426950408889634f;

  // Q resident in registers: frags for 16 d-chunks of 32 (lane = row l15)
  bf16x8 qf[16];
  {
    const unsigned short* qp = QKV + ((long)bat * SEQ + wrow0 + l15) * QKV_LD;
#pragma unroll
    for (int dt = 0; dt < 16; ++dt)
      qf[dt] = *(const bf16x8*)(qp + dt * 32 + quad * 8);
  }
  f32x4 o[32] = {};
  float lacc = 0.f;

  const int kt0 = split * (qt + 1);
  const int kt1 = kt0 + (qt + 1);

  for (int kt = kt0; kt < kt1; ++kt) {
    const int k0 = kt * 32;
    __syncthreads();   // WAR: all waves done reading the buffer

    // stage K (32KB) + V (32KB): 512 threads x 16B x 4 iters each
    {
#pragma unroll
      for (int i = 0; i < 4; ++i) {
        int c = tid + i * 512;
        int krow = c >> 6, chl = c & 63;
        int gch = (chl & 56) | ((chl ^ krow) & 7);
        async_copy16(QKV + ((long)bat * SEQ + k0 + krow) * QKV_LD + 512 + gch * 8,
                     smem + c * 8);
      }
#pragma unroll
      for (int i = 0; i < 4; ++i) {
        int c = tid + i * 512;
        int d = c >> 2, chl = c & 3;
        int gch = (chl - (d >> 1)) & 3;
        async_copy16(Vt + ((long)bat * 512 + d) * SEQ + k0 + gch * 8,
                     smem + 16384 + c * 8);
      }
    }
    __syncthreads();   // drain: staged data visible

    const unsigned short* Ks = smem;
    const unsigned short* Vs = smem + 16384;

    const bool active = (k0 <= wrow0 + 15);
    if (active) {
      // QK^T, swapped: sT = mfma(K, Q) -> lane holds S[k=quad*4+r][q=l15].
      f32x4 s0v = {}, s1v = {};
      __builtin_amdgcn_s_setprio(1);
#pragma unroll
      for (int dt = 0; dt < 16; ++dt) {
        int ch = dt * 4 + quad;
        {
          int krow = l15;
          int chl = (ch & 56) | ((ch ^ krow) & 7);
          bf16x8 kf = *(const bf16x8*)(Ks + krow * 512 + chl * 8);
          s0v = __builtin_amdgcn_mfma_f32_16x16x32_bf16(kf, qf[dt], s0v, 0, 0, 0);
        }
        {
          int krow = 16 + l15;
          int chl = (ch & 56) | ((ch ^ krow) & 7);
          bf16x8 kf = *(const bf16x8*)(Ks + krow * 512 + chl * 8);
          s1v = __builtin_amdgcn_mfma_f32_16x16x32_bf16(kf, qf[dt], s1v, 0, 0, 0);
        }
      }
      __builtin_amdgcn_s_setprio(0);

      const bool diag = (k0 + 31 > wrow0);  // wave-uniform: any masking needed?
      const int qrow = wrow0 + l15;
      float e0[4], e1[4];
#pragma unroll
      for (int r = 0; r < 4; ++r) {
        e0[r] = exp2f(fmaf(s0v[r], C1, C2));
        e1[r] = exp2f(fmaf(s1v[r], C1, C2));
        if (diag) {
          if (k0 + quad * 4 + r > qrow) e0[r] = 0.f;
          if (k0 + 16 + quad * 4 + r > qrow) e1[r] = 0.f;
        }
        lacc += e0[r] + e1[r];
      }
      // pack P to bf16: per-lane words  w0=(k 4q+0,4q+1) w1=(4q+2,4q+3)
      //                                 w2=(16+4q+0,+1)  w3=(16+4q+2,+3)
      unsigned pw0, pw1, pw2, pw3;
      asm("v_cvt_pk_bf16_f32 %0, %1, %2" : "=v"(pw0) : "v"(e0[0]), "v"(e0[1]));
      asm("v_cvt_pk_bf16_f32 %0, %1, %2" : "=v"(pw1) : "v"(e0[2]), "v"(e0[3]));
      asm("v_cvt_pk_bf16_f32 %0, %1, %2" : "=v"(pw2) : "v"(e1[0]), "v"(e1[1]));
      asm("v_cvt_pk_bf16_f32 %0, %1, %2" : "=v"(pw3) : "v"(e1[2]), "v"(e1[3]));
      // redistribute across quads: after these 4 swaps, lane(quad) holds the
      // PV A-frag words [pw0,pw1,pw2,pw3] = P[q=l15][k = quad*8 .. quad*8+7].
      pl32swap(pw0, pw2);
      pl32swap(pw1, pw3);
      pl16swap(pw0, pw2);
      pl16swap(pw1, pw3);
      union { unsigned u[4]; bf16x8 v; } pu;
      pu.u[0] = pw0; pu.u[1] = pw1; pu.u[2] = pw2; pu.u[3] = pw3;
      bf16x8 pf = pu.v;

      __builtin_amdgcn_s_setprio(1);
#pragma unroll
      for (int t = 0; t < 32; ++t) {
        int d = t * 16 + l15;
        int chl = (quad + (d >> 1)) & 3;
        bf16x8 vf = *(const bf16x8*)(Vs + d * 32 + chl * 8);
        o[t] = __builtin_amdgcn_mfma_f32_16x16x32_bf16(pf, vf, o[t], 0, 0, 0);
      }
      __builtin_amdgcn_s_setprio(0);
    }
  }

  // epilogue: reduce l across the 4 quads (lane's 8 k-slots already summed),
  // then broadcast row sums to the o-layout (row = quad*4+r).
  float ps = lacc;
  ps += __shfl_xor(ps, 16);
  ps += __shfl_xor(ps, 32);
  float lrow[4];
#pragma unroll
  for (int r = 0; r < 4; ++r) lrow[r] = __shfl(ps, quad * 4 + r);

  unsigned short* po = (split == 0) ? part0 : (split == 1) ? part1 : (split == 2) ? part2 : part3;
  float* mo = mlbuf + (long)split * 2 * 16384;
  float* lo = mo + 16384;
#pragma unroll
  for (int r = 0; r < 4; ++r) {
    float inv = lrow[r] > 0.f ? 1.0f / lrow[r] : 0.f;
    long row = (long)bat * SEQ + wrow0 + quad * 4 + r;
#pragma unroll
    for (int t = 0; t < 32; ++t)
      po[row * 512 + t * 16 + l15] = f2bf(o[t][r] * inv);
    if (l15 == 0) {
      mo[row] = 12.0f;   // shared static max
      lo[row] = lrow[r];
    }
  }
}

// merge the four split-K partials into ctx (=part0, in place) -- fallback path
__global__ __launch_bounds__(256) void combine4(unsigned short* __restrict__ ctx,
                                                const unsigned short* __restrict__ part1,
                                                const unsigned short* __restrict__ part2,
                                                const unsigned short* __restrict__ part3,
                                                const float* __restrict__ mlbuf)
{
  const float L2E = 1.4426950408889634f;
  int t = blockIdx.x * 256 + threadIdx.x;    // vec8 index over 16384x512
  int row = t >> 6;
  int c8 = (t & 63) * 8;
  float m0 = mlbuf[row],          l0 = mlbuf[16384 + row];
  float m1 = mlbuf[32768 + row],  l1 = mlbuf[49152 + row];
  float m2 = mlbuf[65536 + row],  l2 = mlbuf[81920 + row];
  float m3 = mlbuf[98304 + row],  l3 = mlbuf[114688 + row];
  float m = fmaxf(fmaxf(m0, m1), fmaxf(m2, m3));
  float w0 = l0 * exp2f((m0 - m) * L2E);
  float w1 = l1 * exp2f((m1 - m) * L2E);
  float w2 = l2 * exp2f((m2 - m) * L2E);
  float w3 = l3 * exp2f((m3 - m) * L2E);
  float inv = 1.0f / (w0 + w1 + w2 + w3);   // split 0 always has l>0
  w0 *= inv; w1 *= inv; w2 *= inv; w3 *= inv;
  long off = (long)row * 512 + c8;
  u16x8 a = *(const u16x8*)(ctx + off);
  u16x8 bb = *(const u16x8*)(part1 + off);
  u16x8 cc = *(const u16x8*)(part2 + off);
  u16x8 dd = *(const u16x8*)(part3 + off);
  u16x8 o;
#pragma unroll
  for (int jj = 0; jj < 8; ++jj)
    o[jj] = f2bf(w0 * bf2f(a[jj]) + w1 * bf2f(bb[jj]) + w2 * bf2f(cc[jj]) + w3 * bf2f(dd[jj]));
  *(u16x8*)(ctx + off) = o;
}

// r10: proj GEMM with combine4 FUSED into the A-staging. A-tiles are built by
// loading the 4 partial u16x8s per chunk, combining with per-row weights
// (computed once per block -- each thread's 2 staging rows are fixed across
// all 16 k-steps), and ds_write_b128 into the same swizzled LDS slots the
// async path used. Loads for step t+1 are issued before step t's MFMAs
// (latency hides under compute); writes land after, before the barrier.
__global__ __launch_bounds__(256, 2) void proj_fused(
    const unsigned short* __restrict__ P0, const unsigned short* __restrict__ P1,
    const unsigned short* __restrict__ P2, const unsigned short* __restrict__ P3,
    const float* __restrict__ ml, const unsigned short* __restrict__ Wo,
    float* __restrict__ out)
{
  __shared__ unsigned short As[2][4096];
  __shared__ unsigned short Bs[2][4096];
  const int tid = threadIdx.x;
  const int lane = tid & 63, w = tid >> 6;
  const int l15 = lane & 15, quad = lane >> 4;
  const int wm = w & 1, wn = w >> 1;
  const long m0 = (long)blockIdx.x * 128;
  const long n0 = (long)blockIdx.y * 128;
  const float L2E = 1.4426950408889634f;

  // staging geometry: thread owns rows rA (c=tid) and rB (c=tid+256), fixed.
  const int rA = tid >> 2;
  const int rB = rA + 64;
  const int chl0 = tid & 3;
  const int gchA = (chl0 - (rA >> 1)) & 3;
  const int gchB = (chl0 - (rB >> 1)) & 3;

  float wgt[2][4];
#pragma unroll
  for (int rr = 0; rr < 2; ++rr) {
    long row = m0 + (rr ? rB : rA);
    float mm0 = ml[row],         ll0 = ml[16384 + row];
    float mm1 = ml[32768 + row], ll1 = ml[49152 + row];
    float mm2 = ml[65536 + row], ll2 = ml[81920 + row];
    float mm3 = ml[98304 + row], ll3 = ml[114688 + row];
    float mx = fmaxf(fmaxf(mm0, mm1), fmaxf(mm2, mm3));
    float w0 = ll0 * exp2f((mm0 - mx) * L2E);
    float w1 = ll1 * exp2f((mm1 - mx) * L2E);
    float w2 = ll2 * exp2f((mm2 - mx) * L2E);
    float w3 = ll3 * exp2f((mm3 - mx) * L2E);
    float inv = 1.0f / (w0 + w1 + w2 + w3);
    wgt[rr][0] = w0 * inv; wgt[rr][1] = w1 * inv;
    wgt[rr][2] = w2 * inv; wgt[rr][3] = w3 * inv;
  }

  f32x4 acc[4][4] = {};

#define PLOAD(KT, RR, VA, VB, VC, VD)                                              \
  {                                                                                \
    long off = (m0 + ((RR) ? rB : rA)) * 512 + (KT) * 32 +                         \
               ((RR) ? gchB : gchA) * 8;                                           \
    VA = *(const u16x8*)(P0 + off); VB = *(const u16x8*)(P1 + off);                \
    VC = *(const u16x8*)(P2 + off); VD = *(const u16x8*)(P3 + off);                \
  }
#define PSTORE(BI, RR, CC, VA, VB, VC, VD)                                         \
  {                                                                                \
    u16x8 o8;                                                                      \
    _Pragma("unroll")                                                              \
    for (int jj = 0; jj < 8; ++jj)                                                 \
      o8[jj] = f2bf(wgt[RR][0] * bf2f(VA[jj]) + wgt[RR][1] * bf2f(VB[jj]) +        \
                    wgt[RR][2] * bf2f(VC[jj]) + wgt[RR][3] * bf2f(VD[jj]));        \
    *(u16x8*)(As[BI] + (CC) * 8) = o8;                                             \
  }
#define BSTAGE(KT, BI)                                                             \
  {                                                                                \
    int c = tid;                                                                   \
    int row = c >> 2, ch2 = c & 3;                                                 \
    int gch = (ch2 - (row >> 1)) & 3;                                              \
    async_copy16(Wo + (n0 + row) * 512 + (KT) * 32 + gch * 8, Bs[BI] + c * 8);     \
    c = tid + 256; row = c >> 2; ch2 = c & 3;                                      \
    gch = (ch2 - (row >> 1)) & 3;                                                  \
    async_copy16(Wo + (n0 + row) * 512 + (KT) * 32 + gch * 8, Bs[BI] + c * 8);     \
  }

  // prologue: build A(0) and stage B(0) into buffer 0
  u16x8 pa0, pb0, pc0, pd0, pa1, pb1, pc1, pd1;
  PLOAD(0, 0, pa0, pb0, pc0, pd0);
  PLOAD(0, 1, pa1, pb1, pc1, pd1);
  PSTORE(0, 0, tid, pa0, pb0, pc0, pd0);
  PSTORE(0, 1, tid + 256, pa1, pb1, pc1, pd1);
  BSTAGE(0, 0);

  int bi = 0;
  for (int kt = 0; kt < 16; ++kt) {
    __syncthreads();   // buf bi ready (A writes + B async drained); bi^1 free
    if (kt + 1 < 16) {
      PLOAD(kt + 1, 0, pa0, pb0, pc0, pd0);   // issue early; combine later
      PLOAD(kt + 1, 1, pa1, pb1, pc1, pd1);
      BSTAGE(kt + 1, bi ^ 1);
    }

    bf16x8 af[4], bfr[4];
#pragma unroll
    for (int mt = 0; mt < 4; ++mt) {
      int row = wm * 64 + mt * 16 + l15;
      int chl = (quad + (row >> 1)) & 3;
      af[mt] = *(const bf16x8*)(As[bi] + row * 32 + chl * 8);
    }
#pragma unroll
    for (int nt = 0; nt < 4; ++nt) {
      int row = wn * 64 + nt * 16 + l15;
      int chl = (quad + (row >> 1)) & 3;
      bfr[nt] = *(const bf16x8*)(Bs[bi] + row * 32 + chl * 8);
    }
#pragma unroll
    for (int mt = 0; mt < 4; ++mt)
#pragma unroll
      for (int nt = 0; nt < 4; ++nt)
        acc[mt][nt] = __builtin_amdgcn_mfma_f32_16x16x32_bf16(af[mt], bfr[nt], acc[mt][nt], 0, 0, 0);

    if (kt + 1 < 16) {
      PSTORE(bi ^ 1, 0, tid, pa0, pb0, pc0, pd0);
      PSTORE(bi ^ 1, 1, tid + 256, pa1, pb1, pc1, pd1);
    }
    bi ^= 1;
  }
#undef PLOAD
#undef PSTORE
#undef BSTAGE

#pragma unroll
  for (int mt = 0; mt < 4; ++mt)
#pragma unroll
    for (int nt = 0; nt < 4; ++nt)
#pragma unroll
      for (int r = 0; r < 4; ++r) {
        long row = m0 + wm * 64 + mt * 16 + quad * 4 + r;
        long col = n0 + wn * 64 + nt * 16 + l15;
        out[row * 512 + col] = acc[mt][nt][r];
      }
}

extern "C" void kernel_launch(void* const* d_in, const int* in_sizes, int n_in,
                              void* d_out, int out_size, void* d_ws, size_t ws_size,
                              hipStream_t stream) {
  const float* x  = (const float*)d_in[0];
  const float* Wq = (const float*)d_in[1];
  const float* Wk = (const float*)d_in[2];
  const float* Wv = (const float*)d_in[3];
  const float* Wo = (const float*)d_in[4];
  float* out = (float*)d_out;

  char* ws = (char*)d_ws;
  unsigned short* xb  = (unsigned short*)(ws);                    // 16384x512 bf16 (16.78 MB); dead after gemms -> part1
  unsigned short* wqk = (unsigned short*)(ws + 16777216);         // 1024x512 (1 MB, Wq+Wk); dead after QK gemm -> mlbuf
  unsigned short* wv  = (unsigned short*)(ws + 17825792);         // 512x512 (0.5 MB)
  unsigned short* wo  = (unsigned short*)(ws + 18350080);         // 512x512 (0.5 MB)
  unsigned short* qkv = (unsigned short*)(ws + 18874368);         // 16384x1088 (35.65 MB) -> ends 54525952
  unsigned short* vt  = (unsigned short*)(ws + 54525952);         // 4x512x4096 (16.78 MB) -> ends 71303168
  unsigned short* ctx = (unsigned short*)(ws + 71303168);         // 16384x512 (16.78 MB) -> ends 88080384
  unsigned short* part1 = xb;                                     // reuse (16.78 MB)
  float*          mlbuf = (float*)wqk;                            // reuse (512 KB used)

  // part2/3: in-workspace if it's large enough (enables proj+combine fusion);
  // else fall back to d_out scratch + separate combine4 (d_out can't be both
  // proj output and partial input -- overlapping writes would race).
  const size_t NEED = 121634816ULL;   // ctx end (88080384) + 2x16777216
  const bool fused = ws_size >= NEED;
  unsigned short* part2;
  unsigned short* part3;
  if (fused) {
    part2 = (unsigned short*)(ws + 88080384);
    part3 = (unsigned short*)(ws + 104857600);
  } else {
    part2 = (unsigned short*)d_out;
    part3 = part2 + 8388608;
  }

  (void)hipFuncSetAttribute((const void*)attn,
                            hipFuncAttributeMaxDynamicSharedMemorySize, 65536);

  cvt_all<<<9216, 256, 0, stream>>>(x, Wq, Wk, Wv, Wo, xb, wqk, wv, wo);
  gemm_qkv<<<1536, 256, 0, stream>>>(xb, wqk, qkv, wv, vt);
  attn<<<dim3(512), 512, 65536, stream>>>(qkv, vt, ctx, part1, part2, part3, mlbuf);
  if (fused) {
    proj_fused<<<dim3(128, 4), 256, 0, stream>>>(ctx, part1, part2, part3, mlbuf, wo, out);
  } else {
    combine4<<<4096, 256, 0, stream>>>(ctx, part1, part2, part3, mlbuf);
    gemm_bt<true><<<dim3(128, 4), 256, 0, stream>>>(ctx, wo, out, 512);
  }
}

// Round 14
// 260.054 us; speedup vs baseline: 3.0873x; 3.0873x over previous
//
#include <hip/hip_runtime.h>
#include <cstdint>

typedef __attribute__((ext_vector_type(8))) __bf16 bf16x8;
typedef __attribute__((ext_vector_type(4))) float f32x4;
typedef __attribute__((ext_vector_type(8))) unsigned short u16x8;

#define SEQ 4096
// Q/K row stride in shorts. 1088 = 2176B = 17*128B: NOT a power of two --
// r7 lesson: 1024 (2048B) collapses K-staging rows onto few L2/HBM channels
// (attn 121.5 -> 134.2 us). Odd multiple of 128B rotates rows across channels.
#define QKV_LD 1088
// Vt row stride: SEQ=4096 exactly. r11 lesson: padding to 4160 pushed the
// per-batch Vt slice past the 4 MB per-XCD L2 and cost +16 us. V is protected
// by exact L2 residency.
// r13 lesson: attn per-wave state is ~256 regs (128 VGPR + 128 acc) -> 8
// waves/CU IS the register ceiling; launch_bounds targeting more forces a
// 64-VGPR cap and catastrophic scratch spill (WRITE 66->910 MB).

__device__ __forceinline__ unsigned short f2bf(float f) {
  unsigned u = __builtin_bit_cast(unsigned, f);
  u += 0x7fffu + ((u >> 16) & 1u);
  return (unsigned short)(u >> 16);
}

__device__ __forceinline__ float bf2f(unsigned short h) {
  return __builtin_bit_cast(float, (unsigned)h << 16);
}

// async global->LDS, 16B per lane. LDS dest = wave-uniform base + lane*16.
__device__ __forceinline__ void async_copy16(const void* g, const void* lds) {
  __builtin_amdgcn_global_load_lds(
      (const __attribute__((address_space(1))) void*)(uintptr_t)g,
      (__attribute__((address_space(3))) void*)(unsigned)(uintptr_t)lds,
      16, 0, 0);
}

// cross-lane pair swaps (gfx950). After pl32: a lanes[32:63] <-> b lanes[0:31].
// After pl16: a lanes[16:31] <-> b lanes[0:15] and a[48:63] <-> b[32:47].
__device__ __forceinline__ void pl32swap(unsigned& a, unsigned& b) {
#if __has_builtin(__builtin_amdgcn_permlane32_swap)
  typedef __attribute__((ext_vector_type(2))) unsigned u32x2;
  u32x2 r = __builtin_amdgcn_permlane32_swap(a, b, false, false);
  a = r[0]; b = r[1];
#else
  asm("v_permlane32_swap_b32 %0, %1" : "+v"(a), "+v"(b));
#endif
}
__device__ __forceinline__ void pl16swap(unsigned& a, unsigned& b) {
#if __has_builtin(__builtin_amdgcn_permlane16_swap)
  typedef __attribute__((ext_vector_type(2))) unsigned u32x2;
  u32x2 r = __builtin_amdgcn_permlane16_swap(a, b, false, false);
  a = r[0]; b = r[1];
#else
  asm("v_permlane16_swap_b32 %0, %1" : "+v"(a), "+v"(b));
#endif
}

// single launch: x (8192 blocks) + all four 512x512 weights (1024 blocks)
__global__ void cvt_all(const float* __restrict__ x,
                        const float* __restrict__ Wq, const float* __restrict__ Wk,
                        const float* __restrict__ Wv, const float* __restrict__ Wo,
                        unsigned short* __restrict__ xb, unsigned short* __restrict__ wqk,
                        unsigned short* __restrict__ wv, unsigned short* __restrict__ wo)
{
  int bid = blockIdx.x;
  const float* src; unsigned short* dst; int i;
  if (bid < 8192) {
    src = x; dst = xb; i = (bid * 256 + threadIdx.x) * 4;
  } else {
    int b2 = bid - 8192;          // 0..1023, 256 blocks per weight
    int y = b2 >> 8;
    src = (y == 0) ? Wq : (y == 1) ? Wk : (y == 2) ? Wv : Wo;
    dst = (y == 0) ? wqk : (y == 1) ? wqk + 262144 : (y == 2) ? wv : wo;
    i = ((b2 & 255) * 256 + threadIdx.x) * 4;
  }
  float4 v = *(const float4*)(src + i);
  ushort4 o;
  o.x = f2bf(v.x); o.y = f2bf(v.y); o.z = f2bf(v.z); o.w = f2bf(v.w);
  *(ushort4*)(dst + i) = o;
}

// C[m,n] = sum_k A[m,k] * B[n,k]  (A: lda=512, B: ldb=512, both bf16, K=512)
// Double-buffered k-loop (r9). Used only for the fallback proj path.
template <bool F32OUT>
__global__ __launch_bounds__(256, 2) void gemm_bt(
    const unsigned short* __restrict__ A, const unsigned short* __restrict__ B,
    void* __restrict__ C, int ldc)
{
  __shared__ unsigned short As[2][4096];
  __shared__ unsigned short Bs[2][4096];
  const int tid = threadIdx.x;
  const int lane = tid & 63;
  const int w = tid >> 6;
  const int l15 = lane & 15, quad = lane >> 4;
  const int wm = w & 1, wn = w >> 1;
  const long m0 = (long)blockIdx.x * 128;
  const long n0 = (long)blockIdx.y * 128;

  f32x4 acc[4][4] = {};

#define GB_STAGE(KT, BI)                                                            \
  {                                                                                 \
    int c = tid;                                                                    \
    int row = c >> 2, chl = c & 3;                                                  \
    int gch = (chl - (row >> 1)) & 3;                                               \
    async_copy16(A + (m0 + row) * 512 + (KT) * 32 + gch * 8, As[BI] + c * 8);       \
    async_copy16(B + (n0 + row) * 512 + (KT) * 32 + gch * 8, Bs[BI] + c * 8);       \
    c = tid + 256;                                                                  \
    row = c >> 2; chl = c & 3;                                                      \
    gch = (chl - (row >> 1)) & 3;                                                   \
    async_copy16(A + (m0 + row) * 512 + (KT) * 32 + gch * 8, As[BI] + c * 8);       \
    async_copy16(B + (n0 + row) * 512 + (KT) * 32 + gch * 8, Bs[BI] + c * 8);       \
  }

  GB_STAGE(0, 0);
  int bi = 0;
  for (int kt = 0; kt < 16; ++kt) {
    __syncthreads();
    if (kt + 1 < 16) GB_STAGE(kt + 1, bi ^ 1);

    bf16x8 af[4], bfr[4];
#pragma unroll
    for (int mt = 0; mt < 4; ++mt) {
      int row = wm * 64 + mt * 16 + l15;
      int chl = (quad + (row >> 1)) & 3;
      af[mt] = *(const bf16x8*)(As[bi] + row * 32 + chl * 8);
    }
#pragma unroll
    for (int nt = 0; nt < 4; ++nt) {
      int row = wn * 64 + nt * 16 + l15;
      int chl = (quad + (row >> 1)) & 3;
      bfr[nt] = *(const bf16x8*)(Bs[bi] + row * 32 + chl * 8);
    }
#pragma unroll
    for (int mt = 0; mt < 4; ++mt)
#pragma unroll
      for (int nt = 0; nt < 4; ++nt)
        acc[mt][nt] = __builtin_amdgcn_mfma_f32_16x16x32_bf16(af[mt], bfr[nt], acc[mt][nt], 0, 0, 0);
    bi ^= 1;
  }
#undef GB_STAGE

#pragma unroll
  for (int mt = 0; mt < 4; ++mt)
#pragma unroll
    for (int nt = 0; nt < 4; ++nt)
#pragma unroll
      for (int r = 0; r < 4; ++r) {
        long row = m0 + wm * 64 + mt * 16 + quad * 4 + r;
        long col = n0 + wn * 64 + nt * 16 + l15;
        float v = acc[mt][nt][r];
        if (F32OUT) ((float*)C)[row * ldc + col] = v;
        else        ((unsigned short*)C)[row * ldc + col] = f2bf(v);
      }
}

// Merged QK + V^T GEMM in one launch (r10): blocks 0..1023 compute
// qkv[s][0..1023] = [x@Wq^T | x@Wk^T]; blocks 1024..1535 compute
// Vt[b][d][s] = sum_k Wv[d,k]*x[b,s,k] (row stride SEQ). Same body,
// operands picked per block; V blocks backfill CUs during the QK tail.
__global__ __launch_bounds__(256, 2) void gemm_qkv(
    const unsigned short* __restrict__ xb, const unsigned short* __restrict__ wqk,
    unsigned short* __restrict__ qkv,
    const unsigned short* __restrict__ wv, unsigned short* __restrict__ vt)
{
  __shared__ unsigned short As[2][4096];
  __shared__ unsigned short Bs[2][4096];
  const unsigned short *A, *B;
  unsigned short* C;
  int ldc;
  long m0, n0;
  {
    int bid = blockIdx.x;
    if (bid < 1024) {
      A = xb; B = wqk; C = qkv; ldc = QKV_LD;
      m0 = (long)(bid & 127) * 128;
      n0 = (long)(bid >> 7) * 128;
    } else {
      int b2 = bid - 1024;               // 0..511
      int z = b2 >> 7;                   // batch
      A = wv; B = xb + (long)z * SEQ * 512; C = vt + (long)z * 512 * SEQ; ldc = SEQ;
      m0 = (long)(b2 & 3) * 128;
      n0 = (long)((b2 >> 2) & 31) * 128;
    }
  }
  const int tid = threadIdx.x;
  const int lane = tid & 63;
  const int w = tid >> 6;
  const int l15 = lane & 15, quad = lane >> 4;
  const int wm = w & 1, wn = w >> 1;

  f32x4 acc[4][4] = {};

#define GQ_STAGE(KT, BI)                                                            \
  {                                                                                 \
    int c = tid;                                                                    \
    int row = c >> 2, chl = c & 3;                                                  \
    int gch = (chl - (row >> 1)) & 3;                                               \
    async_copy16(A + (m0 + row) * 512 + (KT) * 32 + gch * 8, As[BI] + c * 8);       \
    async_copy16(B + (n0 + row) * 512 + (KT) * 32 + gch * 8, Bs[BI] + c * 8);       \
    c = tid + 256;                                                                  \
    row = c >> 2; chl = c & 3;                                                      \
    gch = (chl - (row >> 1)) & 3;                                                   \
    async_copy16(A + (m0 + row) * 512 + (KT) * 32 + gch * 8, As[BI] + c * 8);       \
    async_copy16(B + (n0 + row) * 512 + (KT) * 32 + gch * 8, Bs[BI] + c * 8);       \
  }

  GQ_STAGE(0, 0);
  int bi = 0;
  for (int kt = 0; kt < 16; ++kt) {
    __syncthreads();
    if (kt + 1 < 16) GQ_STAGE(kt + 1, bi ^ 1);

    bf16x8 af[4], bfr[4];
#pragma unroll
    for (int mt = 0; mt < 4; ++mt) {
      int row = wm * 64 + mt * 16 + l15;
      int chl = (quad + (row >> 1)) & 3;
      af[mt] = *(const bf16x8*)(As[bi] + row * 32 + chl * 8);
    }
#pragma unroll
    for (int nt = 0; nt < 4; ++nt) {
      int row = wn * 64 + nt * 16 + l15;
      int chl = (quad + (row >> 1)) & 3;
      bfr[nt] = *(const bf16x8*)(Bs[bi] + row * 32 + chl * 8);
    }
#pragma unroll
    for (int mt = 0; mt < 4; ++mt)
#pragma unroll
      for (int nt = 0; nt < 4; ++nt)
        acc[mt][nt] = __builtin_amdgcn_mfma_f32_16x16x32_bf16(af[mt], bfr[nt], acc[mt][nt], 0, 0, 0);
    bi ^= 1;
  }
#undef GQ_STAGE

#pragma unroll
  for (int mt = 0; mt < 4; ++mt)
#pragma unroll
    for (int nt = 0; nt < 4; ++nt)
#pragma unroll
      for (int r = 0; r < 4; ++r) {
        long row = m0 + wm * 64 + mt * 16 + quad * 4 + r;
        long col = n0 + wn * 64 + nt * 16 + l15;
        C[row * ldc + col] = f2bf(acc[mt][nt][r]);
      }
}

// Flash attention, causal. VERIFIED round-2 structure, verbatim (r8/r10/r12):
// Q-tile = 128 rows, 512 threads (8 waves x 16 rows), split-K x4, XCD-aware,
// largest-first, double-buffered K+V (128 KB LDS), STATIC-MAX softmax,
// swapped QK^T, in-register P transpose, per-lane l reduced once.
__global__ __launch_bounds__(512, 2) void attn(const unsigned short* __restrict__ QKV,
                                               const unsigned short* __restrict__ Vt,
                                               unsigned short* __restrict__ part0,
                                               unsigned short* __restrict__ part1,
                                               unsigned short* __restrict__ part2,
                                               unsigned short* __restrict__ part3,
                                               float* __restrict__ mlbuf)
{
  extern __shared__ unsigned short smem[];
  // layout (shorts): K0 @0, K1 @16384, V0 @32768, V1 @49152
  const int tid = threadIdx.x;
  const int lane = tid & 63, w = tid >> 6;
  const int l15 = lane & 15, quad = lane >> 4;

  const int f = blockIdx.x;
  const int xcd = f & 7;
  const int j = f >> 3;            // 0..63 within XCD slice
  const int bat = xcd >> 1;        // batch -> XCD pair
  const int half = xcd & 1;
  int qt, sv;
  if (j < 32) { qt = 31 - j; sv = 0; }   // largest-first in both halves
  else        { qt = 63 - j; sv = 1; }
  const int split = half * 2 + sv;

  const int q0 = qt * 128;
  const int wrow0 = q0 + w * 16;
  // e = exp2(raw * SCALE * log2e - 12 * log2e)
  const float C1 = 0.04419417382415922f * 1.4426950408889634f;
  const float C2 = -12.0f * 1.4426950408889634f;

  // Q resident in registers: frags for 16 d-chunks of 32 (lane = row l15)
  bf16x8 qf[16];
  {
    const unsigned short* qp = QKV + ((long)bat * SEQ + wrow0 + l15) * QKV_LD;
#pragma unroll
    for (int dt = 0; dt < 16; ++dt)
      qf[dt] = *(const bf16x8*)(qp + dt * 32 + quad * 8);
  }
  f32x4 o[32] = {};
  float lacc = 0.f;

  const int kt0 = split * (qt + 1);
  const int kt1 = kt0 + (qt + 1);

#define STAGE_KV(KT, BI)                                                               \
  {                                                                                    \
    unsigned short* Kb = smem + (BI) * 16384;                                          \
    unsigned short* Vb = smem + 32768 + (BI) * 16384;                                  \
    const int kk0 = (KT) * 32;                                                         \
    _Pragma("unroll")                                                                  \
    for (int i = 0; i < 4; ++i) {                                                      \
      int c = tid + i * 512;                                                           \
      int krow = c >> 6, chl = c & 63;                                                 \
      int gch = (chl & 56) | ((chl ^ krow) & 7);                                       \
      async_copy16(QKV + ((long)bat * SEQ + kk0 + krow) * QKV_LD + 512 + gch * 8,      \
                   Kb + c * 8);                                                        \
    }                                                                                  \
    _Pragma("unroll")                                                                  \
    for (int i = 0; i < 4; ++i) {                                                      \
      int c = tid + i * 512;                                                           \
      int d = c >> 2, chl = c & 3;                                                     \
      int gch = (chl - (d >> 1)) & 3;                                                  \
      async_copy16(Vt + ((long)bat * 512 + d) * SEQ + kk0 + gch * 8, Vb + c * 8);      \
    }                                                                                  \
  }

  // prologue: stage kt0 into buffer 0
  STAGE_KV(kt0, 0);

  int bi = 0;
  for (int kt = kt0; kt < kt1; ++kt) {
    const int k0 = kt * 32;
    __syncthreads();  // stage(kt,bi) landed; all waves done reading buf bi^1

    if (kt + 1 < kt1) STAGE_KV(kt + 1, bi ^ 1);

    const unsigned short* Ks = smem + bi * 16384;
    const unsigned short* Vs = smem + 32768 + bi * 16384;

    const bool active = (k0 <= wrow0 + 15);
    if (active) {
      // QK^T, swapped: sT = mfma(K, Q) -> lane holds S[k=quad*4+r][q=l15].
      f32x4 s0v = {}, s1v = {};
      __builtin_amdgcn_s_setprio(1);
#pragma unroll
      for (int dt = 0; dt < 16; ++dt) {
        int ch = dt * 4 + quad;
        {
          int krow = l15;
          int chl = (ch & 56) | ((ch ^ krow) & 7);
          bf16x8 kf = *(const bf16x8*)(Ks + krow * 512 + chl * 8);
          s0v = __builtin_amdgcn_mfma_f32_16x16x32_bf16(kf, qf[dt], s0v, 0, 0, 0);
        }
        {
          int krow = 16 + l15;
          int chl = (ch & 56) | ((ch ^ krow) & 7);
          bf16x8 kf = *(const bf16x8*)(Ks + krow * 512 + chl * 8);
          s1v = __builtin_amdgcn_mfma_f32_16x16x32_bf16(kf, qf[dt], s1v, 0, 0, 0);
        }
      }
      __builtin_amdgcn_s_setprio(0);

      const bool diag = (k0 + 31 > wrow0);  // wave-uniform: any masking needed?
      const int qrow = wrow0 + l15;
      float e0[4], e1[4];
#pragma unroll
      for (int r = 0; r < 4; ++r) {
        e0[r] = exp2f(fmaf(s0v[r], C1, C2));
        e1[r] = exp2f(fmaf(s1v[r], C1, C2));
        if (diag) {
          if (k0 + quad * 4 + r > qrow) e0[r] = 0.f;
          if (k0 + 16 + quad * 4 + r > qrow) e1[r] = 0.f;
        }
        lacc += e0[r] + e1[r];
      }
      // pack P to bf16: per-lane words  w0=(k 4q+0,4q+1) w1=(4q+2,4q+3)
      //                                 w2=(16+4q+0,+1)  w3=(16+4q+2,+3)
      unsigned pw0, pw1, pw2, pw3;
      asm("v_cvt_pk_bf16_f32 %0, %1, %2" : "=v"(pw0) : "v"(e0[0]), "v"(e0[1]));
      asm("v_cvt_pk_bf16_f32 %0, %1, %2" : "=v"(pw1) : "v"(e0[2]), "v"(e0[3]));
      asm("v_cvt_pk_bf16_f32 %0, %1, %2" : "=v"(pw2) : "v"(e1[0]), "v"(e1[1]));
      asm("v_cvt_pk_bf16_f32 %0, %1, %2" : "=v"(pw3) : "v"(e1[2]), "v"(e1[3]));
      // redistribute across quads: after these 4 swaps, lane(quad) holds the
      // PV A-frag words [pw0,pw1,pw2,pw3] = P[q=l15][k = quad*8 .. quad*8+7].
      pl32swap(pw0, pw2);
      pl32swap(pw1, pw3);
      pl16swap(pw0, pw2);
      pl16swap(pw1, pw3);
      union { unsigned u[4]; bf16x8 v; } pu;
      pu.u[0] = pw0; pu.u[1] = pw1; pu.u[2] = pw2; pu.u[3] = pw3;
      bf16x8 pf = pu.v;

      __builtin_amdgcn_s_setprio(1);
#pragma unroll
      for (int t = 0; t < 32; ++t) {
        int d = t * 16 + l15;
        int chl = (quad + (d >> 1)) & 3;
        bf16x8 vf = *(const bf16x8*)(Vs + d * 32 + chl * 8);
        o[t] = __builtin_amdgcn_mfma_f32_16x16x32_bf16(pf, vf, o[t], 0, 0, 0);
      }
      __builtin_amdgcn_s_setprio(0);
    }
    bi ^= 1;
  }
#undef STAGE_KV

  // epilogue: reduce l across the 4 quads (lane's 8 k-slots already summed),
  // then broadcast row sums to the o-layout (row = quad*4+r).
  float ps = lacc;
  ps += __shfl_xor(ps, 16);
  ps += __shfl_xor(ps, 32);
  float lrow[4];
#pragma unroll
  for (int r = 0; r < 4; ++r) lrow[r] = __shfl(ps, quad * 4 + r);

  unsigned short* po = (split == 0) ? part0 : (split == 1) ? part1 : (split == 2) ? part2 : part3;
  float* mo = mlbuf + (long)split * 2 * 16384;
  float* lo = mo + 16384;
#pragma unroll
  for (int r = 0; r < 4; ++r) {
    float inv = lrow[r] > 0.f ? 1.0f / lrow[r] : 0.f;
    long row = (long)bat * SEQ + wrow0 + quad * 4 + r;
#pragma unroll
    for (int t = 0; t < 32; ++t)
      po[row * 512 + t * 16 + l15] = f2bf(o[t][r] * inv);
    if (l15 == 0) {
      mo[row] = 12.0f;   // shared static max
      lo[row] = lrow[r];
    }
  }
}

// merge the four split-K partials into ctx (=part0, in place) -- fallback path
__global__ __launch_bounds__(256) void combine4(unsigned short* __restrict__ ctx,
                                                const unsigned short* __restrict__ part1,
                                                const unsigned short* __restrict__ part2,
                                                const unsigned short* __restrict__ part3,
                                                const float* __restrict__ mlbuf)
{
  const float L2E = 1.4426950408889634f;
  int t = blockIdx.x * 256 + threadIdx.x;    // vec8 index over 16384x512
  int row = t >> 6;
  int c8 = (t & 63) * 8;
  float m0 = mlbuf[row],          l0 = mlbuf[16384 + row];
  float m1 = mlbuf[32768 + row],  l1 = mlbuf[49152 + row];
  float m2 = mlbuf[65536 + row],  l2 = mlbuf[81920 + row];
  float m3 = mlbuf[98304 + row],  l3 = mlbuf[114688 + row];
  float m = fmaxf(fmaxf(m0, m1), fmaxf(m2, m3));
  float w0 = l0 * exp2f((m0 - m) * L2E);
  float w1 = l1 * exp2f((m1 - m) * L2E);
  float w2 = l2 * exp2f((m2 - m) * L2E);
  float w3 = l3 * exp2f((m3 - m) * L2E);
  float inv = 1.0f / (w0 + w1 + w2 + w3);   // split 0 always has l>0
  w0 *= inv; w1 *= inv; w2 *= inv; w3 *= inv;
  long off = (long)row * 512 + c8;
  u16x8 a = *(const u16x8*)(ctx + off);
  u16x8 bb = *(const u16x8*)(part1 + off);
  u16x8 cc = *(const u16x8*)(part2 + off);
  u16x8 dd = *(const u16x8*)(part3 + off);
  u16x8 o;
#pragma unroll
  for (int jj = 0; jj < 8; ++jj)
    o[jj] = f2bf(w0 * bf2f(a[jj]) + w1 * bf2f(bb[jj]) + w2 * bf2f(cc[jj]) + w3 * bf2f(dd[jj]));
  *(u16x8*)(ctx + off) = o;
}

// r10: proj GEMM with combine4 FUSED into the A-staging. A-tiles are built by
// loading the 4 partial u16x8s per chunk, combining with per-row weights
// (computed once per block -- each thread's 2 staging rows are fixed across
// all 16 k-steps), and ds_write_b128 into the same swizzled LDS slots the
// async path used. Loads for step t+1 are issued before step t's MFMAs
// (latency hides under compute); writes land after, before the barrier.
__global__ __launch_bounds__(256, 2) void proj_fused(
    const unsigned short* __restrict__ P0, const unsigned short* __restrict__ P1,
    const unsigned short* __restrict__ P2, const unsigned short* __restrict__ P3,
    const float* __restrict__ ml, const unsigned short* __restrict__ Wo,
    float* __restrict__ out)
{
  __shared__ unsigned short As[2][4096];
  __shared__ unsigned short Bs[2][4096];
  const int tid = threadIdx.x;
  const int lane = tid & 63, w = tid >> 6;
  const int l15 = lane & 15, quad = lane >> 4;
  const int wm = w & 1, wn = w >> 1;
  const long m0 = (long)blockIdx.x * 128;
  const long n0 = (long)blockIdx.y * 128;
  const float L2E = 1.4426950408889634f;

  // staging geometry: thread owns rows rA (c=tid) and rB (c=tid+256), fixed.
  const int rA = tid >> 2;
  const int rB = rA + 64;
  const int chl0 = tid & 3;
  const int gchA = (chl0 - (rA >> 1)) & 3;
  const int gchB = (chl0 - (rB >> 1)) & 3;

  float wgt[2][4];
#pragma unroll
  for (int rr = 0; rr < 2; ++rr) {
    long row = m0 + (rr ? rB : rA);
    float mm0 = ml[row],         ll0 = ml[16384 + row];
    float mm1 = ml[32768 + row], ll1 = ml[49152 + row];
    float mm2 = ml[65536 + row], ll2 = ml[81920 + row];
    float mm3 = ml[98304 + row], ll3 = ml[114688 + row];
    float mx = fmaxf(fmaxf(mm0, mm1), fmaxf(mm2, mm3));
    float w0 = ll0 * exp2f((mm0 - mx) * L2E);
    float w1 = ll1 * exp2f((mm1 - mx) * L2E);
    float w2 = ll2 * exp2f((mm2 - mx) * L2E);
    float w3 = ll3 * exp2f((mm3 - mx) * L2E);
    float inv = 1.0f / (w0 + w1 + w2 + w3);
    wgt[rr][0] = w0 * inv; wgt[rr][1] = w1 * inv;
    wgt[rr][2] = w2 * inv; wgt[rr][3] = w3 * inv;
  }

  f32x4 acc[4][4] = {};

#define PLOAD(KT, RR, VA, VB, VC, VD)                                              \
  {                                                                                \
    long off = (m0 + ((RR) ? rB : rA)) * 512 + (KT) * 32 +                         \
               ((RR) ? gchB : gchA) * 8;                                           \
    VA = *(const u16x8*)(P0 + off); VB = *(const u16x8*)(P1 + off);                \
    VC = *(const u16x8*)(P2 + off); VD = *(const u16x8*)(P3 + off);                \
  }
#define PSTORE(BI, RR, CC, VA, VB, VC, VD)                                         \
  {                                                                                \
    u16x8 o8;                                                                      \
    _Pragma("unroll")                                                              \
    for (int jj = 0; jj < 8; ++jj)                                                 \
      o8[jj] = f2bf(wgt[RR][0] * bf2f(VA[jj]) + wgt[RR][1] * bf2f(VB[jj]) +        \
                    wgt[RR][2] * bf2f(VC[jj]) + wgt[RR][3] * bf2f(VD[jj]));        \
    *(u16x8*)(As[BI] + (CC) * 8) = o8;                                             \
  }
#define BSTAGE(KT, BI)                                                             \
  {                                                                                \
    int c = tid;                                                                   \
    int row = c >> 2, ch2 = c & 3;                                                 \
    int gch = (ch2 - (row >> 1)) & 3;                                              \
    async_copy16(Wo + (n0 + row) * 512 + (KT) * 32 + gch * 8, Bs[BI] + c * 8);     \
    c = tid + 256; row = c >> 2; ch2 = c & 3;                                      \
    gch = (ch2 - (row >> 1)) & 3;                                                  \
    async_copy16(Wo + (n0 + row) * 512 + (KT) * 32 + gch * 8, Bs[BI] + c * 8);     \
  }

  // prologue: build A(0) and stage B(0) into buffer 0
  u16x8 pa0, pb0, pc0, pd0, pa1, pb1, pc1, pd1;
  PLOAD(0, 0, pa0, pb0, pc0, pd0);
  PLOAD(0, 1, pa1, pb1, pc1, pd1);
  PSTORE(0, 0, tid, pa0, pb0, pc0, pd0);
  PSTORE(0, 1, tid + 256, pa1, pb1, pc1, pd1);
  BSTAGE(0, 0);

  int bi = 0;
  for (int kt = 0; kt < 16; ++kt) {
    __syncthreads();   // buf bi ready (A writes + B async drained); bi^1 free
    if (kt + 1 < 16) {
      PLOAD(kt + 1, 0, pa0, pb0, pc0, pd0);   // issue early; combine later
      PLOAD(kt + 1, 1, pa1, pb1, pc1, pd1);
      BSTAGE(kt + 1, bi ^ 1);
    }

    bf16x8 af[4], bfr[4];
#pragma unroll
    for (int mt = 0; mt < 4; ++mt) {
      int row = wm * 64 + mt * 16 + l15;
      int chl = (quad + (row >> 1)) & 3;
      af[mt] = *(const bf16x8*)(As[bi] + row * 32 + chl * 8);
    }
#pragma unroll
    for (int nt = 0; nt < 4; ++nt) {
      int row = wn * 64 + nt * 16 + l15;
      int chl = (quad + (row >> 1)) & 3;
      bfr[nt] = *(const bf16x8*)(Bs[bi] + row * 32 + chl * 8);
    }
#pragma unroll
    for (int mt = 0; mt < 4; ++mt)
#pragma unroll
      for (int nt = 0; nt < 4; ++nt)
        acc[mt][nt] = __builtin_amdgcn_mfma_f32_16x16x32_bf16(af[mt], bfr[nt], acc[mt][nt], 0, 0, 0);

    if (kt + 1 < 16) {
      PSTORE(bi ^ 1, 0, tid, pa0, pb0, pc0, pd0);
      PSTORE(bi ^ 1, 1, tid + 256, pa1, pb1, pc1, pd1);
    }
    bi ^= 1;
  }
#undef PLOAD
#undef PSTORE
#undef BSTAGE

#pragma unroll
  for (int mt = 0; mt < 4; ++mt)
#pragma unroll
    for (int nt = 0; nt < 4; ++nt)
#pragma unroll
      for (int r = 0; r < 4; ++r) {
        long row = m0 + wm * 64 + mt * 16 + quad * 4 + r;
        long col = n0 + wn * 64 + nt * 16 + l15;
        out[row * 512 + col] = acc[mt][nt][r];
      }
}

extern "C" void kernel_launch(void* const* d_in, const int* in_sizes, int n_in,
                              void* d_out, int out_size, void* d_ws, size_t ws_size,
                              hipStream_t stream) {
  const float* x  = (const float*)d_in[0];
  const float* Wq = (const float*)d_in[1];
  const float* Wk = (const float*)d_in[2];
  const float* Wv = (const float*)d_in[3];
  const float* Wo = (const float*)d_in[4];
  float* out = (float*)d_out;

  char* ws = (char*)d_ws;
  unsigned short* xb  = (unsigned short*)(ws);                    // 16384x512 bf16 (16.78 MB); dead after gemms -> part1
  unsigned short* wqk = (unsigned short*)(ws + 16777216);         // 1024x512 (1 MB, Wq+Wk); dead after QK gemm -> mlbuf
  unsigned short* wv  = (unsigned short*)(ws + 17825792);         // 512x512 (0.5 MB)
  unsigned short* wo  = (unsigned short*)(ws + 18350080);         // 512x512 (0.5 MB)
  unsigned short* qkv = (unsigned short*)(ws + 18874368);         // 16384x1088 (35.65 MB) -> ends 54525952
  unsigned short* vt  = (unsigned short*)(ws + 54525952);         // 4x512x4096 (16.78 MB) -> ends 71303168
  unsigned short* ctx = (unsigned short*)(ws + 71303168);         // 16384x512 (16.78 MB) -> ends 88080384
  unsigned short* part1 = xb;                                     // reuse (16.78 MB)
  float*          mlbuf = (float*)wqk;                            // reuse (512 KB used)

  // part2/3: in-workspace if it's large enough (enables proj+combine fusion);
  // else fall back to d_out scratch + separate combine4 (d_out can't be both
  // proj output and partial input -- overlapping writes would race).
  const size_t NEED = 121634816ULL;   // ctx end (88080384) + 2x16777216
  const bool fused = ws_size >= NEED;
  unsigned short* part2;
  unsigned short* part3;
  if (fused) {
    part2 = (unsigned short*)(ws + 88080384);
    part3 = (unsigned short*)(ws + 104857600);
  } else {
    part2 = (unsigned short*)d_out;
    part3 = part2 + 8388608;
  }

  // allow >64KB dynamic LDS (no-op / harmless if unsupported)
  (void)hipFuncSetAttribute((const void*)attn,
                            hipFuncAttributeMaxDynamicSharedMemorySize, 131072);

  cvt_all<<<9216, 256, 0, stream>>>(x, Wq, Wk, Wv, Wo, xb, wqk, wv, wo);
  gemm_qkv<<<1536, 256, 0, stream>>>(xb, wqk, qkv, wv, vt);
  attn<<<dim3(512), 512, 131072, stream>>>(qkv, vt, ctx, part1, part2, part3, mlbuf);
  if (fused) {
    proj_fused<<<dim3(128, 4), 256, 0, stream>>>(ctx, part1, part2, part3, mlbuf, wo, out);
  } else {
    combine4<<<4096, 256, 0, stream>>>(ctx, part1, part2, part3, mlbuf);
    gemm_bt<true><<<dim3(128, 4), 256, 0, stream>>>(ctx, wo, out, 512);
  }
}